// Round 15
// baseline (545.302 us; speedup 1.0000x reference)
//
#include <hip/hip_runtime.h>
#include <hip/hip_bf16.h>
#include <stdint.h>

#define DEV static __device__ __forceinline__

typedef __attribute__((ext_vector_type(8))) short short8;
typedef __attribute__((ext_vector_type(4))) float f32x4;
typedef __attribute__((address_space(3))) void lds_void;
typedef __attribute__((address_space(1))) void glb_void;

constexpr int CB = 2, CL = 2048, CH = 2048, CDI = 4096, CN = 16, CDTR = 128;
constexpr int BLR = CB * CL;   // 4096 total rows (b,l)
constexpr int NC = 32, LC = 64;  // scan chunks x chunk length
constexpr int KSL = 4;           // GEMM2 split-K slices

DEV ushort f2b(float f) {
  union { float f; uint32_t u; } v; v.f = f;
  uint32_t u = v.u;
  return (ushort)((u + 0x7fffu + ((u >> 16) & 1u)) >> 16);
}
DEV float b2f(ushort b) {
  union { uint32_t u; float f; } v; v.u = ((uint32_t)b) << 16;
  return v.f;
}
DEV void gload16(const ushort* g, ushort* l) {
  __builtin_amdgcn_global_load_lds((const glb_void*)g, (lds_void*)l, 16, 0, 0);
}
DEV f32x4 mfma16(short8 a, short8 b, f32x4 c) {
  return __builtin_amdgcn_mfma_f32_16x16x32_bf16(a, b, c, 0, 0, 0);
}

// ---------------- fused casts (x, in_w, dt_w, xproj-pad) ----------------
constexpr int N4_X  = BLR * CH / 4;
constexpr int N4_W1 = 2 * CDI * CH / 4;
constexpr int N4_DT = CDI * CDTR / 4;
constexpr int N4_XP = 256 * 4096 / 4;
__global__ void cast_all_kernel(const float* __restrict__ x, const float* __restrict__ in_w,
                                const float* __restrict__ dt_w, const float* __restrict__ xp_w,
                                ushort* __restrict__ xb, ushort* __restrict__ wb1,
                                ushort* __restrict__ wdt, ushort* __restrict__ wxp) {
  int i = blockIdx.x * 256 + threadIdx.x;
  const float* src; ushort* dst; int idx;
  if (i < N4_X) { src = x; dst = xb; idx = i; }
  else if (i < N4_X + N4_W1) { src = in_w; dst = wb1; idx = i - N4_X; }
  else if (i < N4_X + N4_W1 + N4_DT) { src = dt_w; dst = wdt; idx = i - N4_X - N4_W1; }
  else {
    idx = i - (N4_X + N4_W1 + N4_DT);
    if (idx >= N4_XP) return;
    int e = idx * 4;
    int rr = e >> 12;
    ushort4 o;
    if (rr < 160) {
      float4 v = *(const float4*)(xp_w + e);
      o = make_ushort4(f2b(v.x), f2b(v.y), f2b(v.z), f2b(v.w));
    } else o = make_ushort4(0, 0, 0, 0);
    *(ushort4*)(wxp + e) = o;
    return;
  }
  float4 v = *(const float4*)(src + (size_t)idx * 4);
  *(ushort4*)(dst + (size_t)idx * 4) = make_ushort4(f2b(v.x), f2b(v.y), f2b(v.z), f2b(v.w));
}

__global__ void cast_kernel(const float* __restrict__ in, ushort* __restrict__ out, int n4) {
  int i = blockIdx.x * blockDim.x + threadIdx.x;
  if (i >= n4) return;
  float4 v = *(const float4*)(in + (size_t)i * 4);
  *(ushort4*)(out + (size_t)i * 4) = make_ushort4(f2b(v.x), f2b(v.y), f2b(v.z), f2b(v.w));
}

// ---------------- depthwise causal conv1d + silu (8 d / thread) ----------------
__global__ void conv_silu_kernel(const ushort* __restrict__ xr, const float* __restrict__ w,
                                 const float* __restrict__ bias, ushort* __restrict__ u) {
  int t = blockIdx.x * blockDim.x + threadIdx.x;
  if (t >= BLR * CDI / 8) return;
  const int d8 = (t & (CDI / 8 - 1)) << 3;
  const int bl = t >> 9;
  const int l = bl & (CL - 1);
  float a[8];
  {
    float4 b0 = *(const float4*)(bias + d8);
    float4 b1 = *(const float4*)(bias + d8 + 4);
    a[0] = b0.x; a[1] = b0.y; a[2] = b0.z; a[3] = b0.w;
    a[4] = b1.x; a[5] = b1.y; a[6] = b1.z; a[7] = b1.w;
  }
  float wk[8][4];
#pragma unroll
  for (int j = 0; j < 8; ++j) {
    float4 wj = *(const float4*)(w + (size_t)(d8 + j) * 4);
    wk[j][0] = wj.x; wk[j][1] = wj.y; wk[j][2] = wj.z; wk[j][3] = wj.w;
  }
#pragma unroll
  for (int k = 0; k < 4; ++k) {
    if (l - 3 + k >= 0) {
      short8 xv = *(const short8*)(xr + (size_t)(bl - 3 + k) * 8192 + d8);
#pragma unroll
      for (int j = 0; j < 8; ++j)
        a[j] = fmaf(wk[j][k], b2f((ushort)xv[j]), a[j]);
    }
  }
  short8 o;
#pragma unroll
  for (int j = 0; j < 8; ++j) {
    float s = a[j] / (1.f + __expf(-a[j]));
    o[j] = (short)f2b(s);
  }
  *(short8*)(u + (size_t)bl * 4096 + d8) = o;
}

// ---------------- 256x256 4-phase pipelined GEMM (GEMM1; proven R7) ----------------
template<int EPI>
__global__ __launch_bounds__(512, 1)
void gemm256p_kernel(const ushort* __restrict__ A, const ushort* __restrict__ Bw,
                     void* __restrict__ Cp, int N, int K) {
  __shared__ ushort sA[2][16384];
  __shared__ ushort sB[2][16384];
  const int tid = threadIdx.x;
  const int bm = blockIdx.x, bn = blockIdx.y;
  const int wid = tid >> 6, l = tid & 63;
  const int wr = wid >> 2, wc = wid & 3;
  const int q = l >> 4, r = l & 15;
  const int rx = r & 7;
  const int nt = K >> 6;

  const ushort* Ab = A + (size_t)bm * 256 * K;
  const ushort* Bb = Bw + (size_t)bn * 256 * K;

  const int srow = tid >> 3;
  const int sxor = (tid & 7) ^ (srow & 7);

  auto stageA = [&](int T, int j) {
    const int Ts = (T < nt) ? T : (nt - 1);
    gload16(Ab + (size_t)(j * 64 + srow) * K + Ts * 64 + sxor * 8,
            &sA[T & 1][0] + j * 4096 + tid * 8);
  };
  auto stageB = [&](int T, int j) {
    const int Ts = (T < nt) ? T : (nt - 1);
    gload16(Bb + (size_t)(j * 64 + srow) * K + Ts * 64 + sxor * 8,
            &sB[T & 1][0] + j * 4096 + tid * 8);
  };

  const int sl0 = (q ^ rx) * 8;
  const int sl1 = ((4 + q) ^ rx) * 8;

  f32x4 acc[8][4] = {};

  stageA(0, 1); stageA(0, 3);
  stageB(0, 0); stageA(0, 0);
  stageB(0, 2); stageA(0, 2);
  stageB(0, 1); stageB(0, 3);
  stageA(1, 1); stageA(1, 3);
  asm volatile("s_waitcnt vmcnt(2)" ::: "memory");
  __builtin_amdgcn_s_barrier();

#define PHASE(M0, M1, S0, S1, LAST)                                        \
  {                                                                        \
    const int ra0 = (wr * 128 + (M0) * 16 + r) * 64;                       \
    const int ra1 = (wr * 128 + (M1) * 16 + r) * 64;                       \
    short8 a00 = *(const short8*)(At + ra0 + sl0);                         \
    short8 a01 = *(const short8*)(At + ra0 + sl1);                         \
    short8 a10 = *(const short8*)(At + ra1 + sl0);                         \
    short8 a11 = *(const short8*)(At + ra1 + sl1);                         \
    S0; S1;                                                                \
    if (LAST) asm volatile("s_waitcnt vmcnt(2)" ::: "memory");             \
    __builtin_amdgcn_s_barrier();                                          \
    asm volatile("s_waitcnt lgkmcnt(0)" ::: "memory");                     \
    __builtin_amdgcn_sched_barrier(0);                                     \
    __builtin_amdgcn_s_setprio(1);                                         \
    _Pragma("unroll")                                                      \
    for (int n = 0; n < 4; ++n) {                                          \
      acc[M0][n] = mfma16(a00, bf[n][0], acc[M0][n]);                      \
      acc[M0][n] = mfma16(a01, bf[n][1], acc[M0][n]);                      \
      acc[M1][n] = mfma16(a10, bf[n][0], acc[M1][n]);                      \
      acc[M1][n] = mfma16(a11, bf[n][1], acc[M1][n]);                      \
    }                                                                      \
    __builtin_amdgcn_s_setprio(0);                                         \
    __builtin_amdgcn_sched_barrier(0);                                     \
    __builtin_amdgcn_s_barrier();                                          \
  }

  for (int t = 0; t < nt; ++t) {
    const ushort* At = &sA[t & 1][0];
    const ushort* Bt = &sB[t & 1][0];
    short8 bf[4][2];
#pragma unroll
    for (int n = 0; n < 4; ++n) {
      const int br = (wc * 64 + n * 16 + r) * 64;
      bf[n][0] = *(const short8*)(Bt + br + sl0);
      bf[n][1] = *(const short8*)(Bt + br + sl1);
    }
    PHASE(6, 7, stageB(t + 1, 0), stageA(t + 1, 0), false)
    PHASE(4, 5, stageB(t + 1, 2), stageA(t + 1, 2), false)
    PHASE(2, 3, stageB(t + 1, 1), stageB(t + 1, 3), false)
    PHASE(0, 1, stageA(t + 2, 1), stageA(t + 2, 3), true)
  }
#undef PHASE

  const int m0g = bm * 256 + wr * 128;
  const int n0g = bn * 256 + wc * 64;
#pragma unroll
  for (int m = 0; m < 8; ++m)
#pragma unroll
    for (int n = 0; n < 4; ++n)
#pragma unroll
      for (int v = 0; v < 4; ++v) {
        const int grow = m0g + m * 16 + q * 4 + v;
        const int gcol = n0g + n * 16 + r;
        if (EPI == 0) ((ushort*)Cp)[(size_t)grow * N + gcol] = f2b(acc[m][n][v]);
        else          ((float*)Cp)[(size_t)grow * N + gcol]  = acc[m][n][v];
      }
}

// ---------------- GEMM4: 128x256 2-phase, 3-buffer LDS ring (proven R11) --------
template<int EPI>
__global__ __launch_bounds__(512, 1)
void gemm128x256_kernel(const ushort* __restrict__ A, const ushort* __restrict__ Bw,
                        void* __restrict__ Cp, int N, int K) {
  __shared__ ushort sA[3][8192];
  __shared__ ushort sB[3][16384];
  const int tid = threadIdx.x;
  const int bm = blockIdx.x, bn = blockIdx.y;
  const int wid = tid >> 6, l = tid & 63;
  const int wr = wid >> 2, wc = wid & 3;
  const int q = l >> 4, r = l & 15;
  const int rx = r & 7;
  const int nt = K >> 6;

  const ushort* Ab = A + (size_t)bm * 128 * K;
  const ushort* Bb = Bw + (size_t)bn * 256 * K;

  const int srow = tid >> 3;
  const int sxor = (tid & 7) ^ (srow & 7);

  auto stageA = [&](int T, int buf, int j) {
    const int Ts = (T < nt) ? T : (nt - 1);
    gload16(Ab + (size_t)(j * 64 + srow) * K + Ts * 64 + sxor * 8,
            &sA[buf][0] + j * 4096 + tid * 8);
  };
  auto stageB = [&](int T, int buf, int j) {
    const int Ts = (T < nt) ? T : (nt - 1);
    gload16(Bb + (size_t)(j * 64 + srow) * K + Ts * 64 + sxor * 8,
            &sB[buf][0] + j * 4096 + tid * 8);
  };

  const int sl0 = (q ^ rx) * 8;
  const int sl1 = ((4 + q) ^ rx) * 8;

  f32x4 acc[4][4] = {};

  stageA(0, 0, 0); stageA(0, 0, 1);
  stageB(0, 0, 0); stageB(0, 0, 1); stageB(0, 0, 2); stageB(0, 0, 3);
  stageA(1, 1, 0); stageA(1, 1, 1);
  asm volatile("s_waitcnt vmcnt(2)" ::: "memory");
  __builtin_amdgcn_s_barrier();

  int c0 = 0;
  for (int t = 0; t < nt; ++t) {
    const int c1 = (c0 == 2) ? 0 : c0 + 1;
    const int c2 = (c1 == 2) ? 0 : c1 + 1;
    const ushort* At = &sA[c0][0];
    const ushort* Bt = &sB[c0][0];
    short8 bf[4][2];
#pragma unroll
    for (int n = 0; n < 4; ++n) {
      const int br = (wc * 64 + n * 16 + r) * 64;
      bf[n][0] = *(const short8*)(Bt + br + sl0);
      bf[n][1] = *(const short8*)(Bt + br + sl1);
    }
    {
      const int ra0 = (wr * 64 + 2 * 16 + r) * 64;
      const int ra1 = (wr * 64 + 3 * 16 + r) * 64;
      short8 a00 = *(const short8*)(At + ra0 + sl0);
      short8 a01 = *(const short8*)(At + ra0 + sl1);
      short8 a10 = *(const short8*)(At + ra1 + sl0);
      short8 a11 = *(const short8*)(At + ra1 + sl1);
      stageB(t + 1, c1, 0); stageB(t + 1, c1, 1); stageB(t + 1, c1, 2);
      __builtin_amdgcn_s_barrier();
      asm volatile("s_waitcnt lgkmcnt(0)" ::: "memory");
      __builtin_amdgcn_sched_barrier(0);
      __builtin_amdgcn_s_setprio(1);
#pragma unroll
      for (int n = 0; n < 4; ++n) {
        acc[2][n] = mfma16(a00, bf[n][0], acc[2][n]);
        acc[2][n] = mfma16(a01, bf[n][1], acc[2][n]);
        acc[3][n] = mfma16(a10, bf[n][0], acc[3][n]);
        acc[3][n] = mfma16(a11, bf[n][1], acc[3][n]);
      }
      __builtin_amdgcn_s_setprio(0);
      __builtin_amdgcn_sched_barrier(0);
      __builtin_amdgcn_s_barrier();
    }
    {
      const int ra0 = (wr * 64 + 0 * 16 + r) * 64;
      const int ra1 = (wr * 64 + 1 * 16 + r) * 64;
      short8 a00 = *(const short8*)(At + ra0 + sl0);
      short8 a01 = *(const short8*)(At + ra0 + sl1);
      short8 a10 = *(const short8*)(At + ra1 + sl0);
      short8 a11 = *(const short8*)(At + ra1 + sl1);
      stageB(t + 1, c1, 3); stageA(t + 2, c2, 0); stageA(t + 2, c2, 1);
      asm volatile("s_waitcnt vmcnt(2)" ::: "memory");
      __builtin_amdgcn_s_barrier();
      asm volatile("s_waitcnt lgkmcnt(0)" ::: "memory");
      __builtin_amdgcn_sched_barrier(0);
      __builtin_amdgcn_s_setprio(1);
#pragma unroll
      for (int n = 0; n < 4; ++n) {
        acc[0][n] = mfma16(a00, bf[n][0], acc[0][n]);
        acc[0][n] = mfma16(a01, bf[n][1], acc[0][n]);
        acc[1][n] = mfma16(a10, bf[n][0], acc[1][n]);
        acc[1][n] = mfma16(a11, bf[n][1], acc[1][n]);
      }
      __builtin_amdgcn_s_setprio(0);
      __builtin_amdgcn_sched_barrier(0);
      __builtin_amdgcn_s_barrier();
    }
    c0 = c1;
  }

  const int m0g = bm * 128 + wr * 64;
  const int n0g = bn * 256 + wc * 64;
#pragma unroll
  for (int m = 0; m < 4; ++m)
#pragma unroll
    for (int n = 0; n < 4; ++n)
#pragma unroll
      for (int v = 0; v < 4; ++v) {
        const int grow = m0g + m * 16 + q * 4 + v;
        const int gcol = n0g + n * 16 + r;
        if (EPI == 0) ((ushort*)Cp)[(size_t)grow * N + gcol] = f2b(acc[m][n][v]);
        else          ((float*)Cp)[(size_t)grow * N + gcol]  = acc[m][n][v];
      }
}

// ---------------- GEMM3: single-K-tile 256x256, BK=128 (whole K in LDS) ----------
__global__ __launch_bounds__(512, 1)
void gemm3_kernel(const ushort* __restrict__ A, const ushort* __restrict__ Bw,
                  ushort* __restrict__ Cp, const float* __restrict__ bias) {
  __shared__ ushort sA[256 * 128];
  __shared__ ushort sB[256 * 128];
  const int tid = threadIdx.x;
  const int bm = blockIdx.x, bn = blockIdx.y;
  const int wid = tid >> 6, l = tid & 63;
  const int wr = wid >> 2, wc = wid & 3;
  const int q = l >> 4, r = l & 15;

  const ushort* Ab = A + (size_t)bm * 256 * 128;
  const ushort* Bb = Bw + (size_t)bn * 256 * 128;
#pragma unroll
  for (int i = 0; i < 8; ++i) {
    const int c = i * 512 + tid;
    const int row = c >> 4, p = c & 15;
    const int lsl = p ^ (row & 7);
    gload16(Ab + (size_t)row * 128 + lsl * 8, sA + c * 8);
    gload16(Bb + (size_t)row * 128 + lsl * 8, sB + c * 8);
  }
  __syncthreads();

  f32x4 acc[8][4] = {};
  short8 bf[4][4];
#pragma unroll
  for (int n = 0; n < 4; ++n) {
    const int brow = wc * 64 + n * 16 + r;
#pragma unroll
    for (int ks = 0; ks < 4; ++ks) {
      const int p = (ks * 4 + q) ^ (brow & 7);
      bf[n][ks] = *(const short8*)(sB + brow * 128 + p * 8);
    }
  }
#pragma unroll
  for (int m = 0; m < 8; ++m) {
    const int arow = wr * 128 + m * 16 + r;
    short8 af[4];
#pragma unroll
    for (int ks = 0; ks < 4; ++ks) {
      const int p = (ks * 4 + q) ^ (arow & 7);
      af[ks] = *(const short8*)(sA + arow * 128 + p * 8);
    }
#pragma unroll
    for (int ks = 0; ks < 4; ++ks)
#pragma unroll
      for (int n = 0; n < 4; ++n)
        acc[m][n] = mfma16(af[ks], bf[n][ks], acc[m][n]);
  }

  const int m0g = bm * 256 + wr * 128;
  const int n0g = bn * 256 + wc * 64;
#pragma unroll
  for (int m = 0; m < 8; ++m)
#pragma unroll
    for (int n = 0; n < 4; ++n)
#pragma unroll
      for (int v = 0; v < 4; ++v) {
        const int grow = m0g + m * 16 + q * 4 + v;
        const int gcol = n0g + n * 16 + r;
        float xv = acc[m][n][v] + bias[gcol];
        float sp = xv > 20.f ? xv : log1pf(__expf(xv));
        Cp[(size_t)grow * 4096 + gcol] = f2b(sp);
      }
}

// ---------------- split-K GEMM (GEMM2) ----------------
__global__ __launch_bounds__(256, 4)
void gemm_btk_kernel(const ushort* __restrict__ A, const ushort* __restrict__ Bw,
                     float* __restrict__ Cpart, int N, int Ktot, int Ksl) {
  __shared__ ushort sA[128 * 32];
  __shared__ ushort sB[128 * 32];
  const int tid = threadIdx.x;
  const int bm = blockIdx.x, bn = blockIdx.y, z = blockIdx.z;
  const int w = tid >> 6, l = tid & 63;
  const int wr = w >> 1, wc = w & 1;
  const int q = l >> 4, r = l & 15;

  f32x4 acc[4][4] = {};

  const ushort* Ab = A + (size_t)bm * 128 * Ktot + z * Ksl;
  const ushort* Bb = Bw + (size_t)bn * 128 * Ktot + z * Ksl;
  const int nk = Ksl >> 5;
  for (int kt = 0; kt < nk; ++kt) {
    const int k0 = kt << 5;
#pragma unroll
    for (int i = 0; i < 2; ++i) {
      const int chunk = i * 256 + tid;
      const int row = chunk >> 2;
      const int cofs = (chunk & 3) << 3;
      gload16(Ab + (size_t)row * Ktot + k0 + cofs, sA + chunk * 8);
      gload16(Bb + (size_t)row * Ktot + k0 + cofs, sB + chunk * 8);
    }
    __syncthreads();
    short8 af[4], bfg[4];
#pragma unroll
    for (int i = 0; i < 4; ++i) {
      af[i]  = *(const short8*)(sA + (wr * 64 + i * 16 + r) * 32 + q * 8);
      bfg[i] = *(const short8*)(sB + (wc * 64 + i * 16 + r) * 32 + q * 8);
    }
#pragma unroll
    for (int i = 0; i < 4; ++i)
#pragma unroll
      for (int j = 0; j < 4; ++j)
        acc[i][j] = mfma16(af[i], bfg[j], acc[i][j]);
    __syncthreads();
  }

  float* Cz = Cpart + (size_t)z * BLR * N;
  const int m0 = bm * 128 + wr * 64;
  const int n0 = bn * 128 + wc * 64;
#pragma unroll
  for (int i = 0; i < 4; ++i)
#pragma unroll
    for (int j = 0; j < 4; ++j)
#pragma unroll
      for (int v = 0; v < 4; ++v)
        Cz[(size_t)(m0 + i * 16 + q * 4 + v) * N + (n0 + j * 16 + r)] = acc[i][j][v];
}

__global__ __launch_bounds__(256)
void reduce_xdbl_kernel(const float* __restrict__ part, float* __restrict__ xdbl,
                        ushort* __restrict__ dlt) {
  const int i = blockIdx.x * 256 + threadIdx.x;
  const int idx = i * 4;
  const int row = idx >> 8, col = idx & 255;
  float4 s = make_float4(0.f, 0.f, 0.f, 0.f);
#pragma unroll
  for (int z = 0; z < KSL; ++z) {
    float4 v = *(const float4*)(part + (size_t)z * BLR * 256 + idx);
    s.x += v.x; s.y += v.y; s.z += v.z; s.w += v.w;
  }
  *(float4*)(xdbl + idx) = s;
  if (col < 128) {
    *(ushort4*)(dlt + (size_t)row * 128 + col) =
        make_ushort4(f2b(s.x), f2b(s.y), f2b(s.z), f2b(s.w));
  }
}

// ---------------- chunk-parallel selective scan (LDS-staged tiles) ----------------
__global__ __launch_bounds__(256)
void scan_pass1_kernel(const ushort* __restrict__ delta_bf, const ushort* __restrict__ u_bf,
                       const float* __restrict__ xdbl, const float* __restrict__ A_log,
                       float* __restrict__ Hc, float* __restrict__ Ssum) {
  __shared__ ushort sD[LC * 256];
  __shared__ ushort sU[LC * 256];
  __shared__ float4 sB[LC * 4];
  const int blk = blockIdx.x;
  const int dblk = blk & 15, bc = blk >> 4;
  const int b = bc & (CB - 1), c = bc >> 1;
  const int tid = threadIdx.x;
  const int d = dblk * 256 + tid;
  const size_t rowbase = (size_t)b * CL + c * LC;

  // bulk-stage the whole chunk tile: [64 t][256 d] for delta and u
  const ushort* dbase = delta_bf + rowbase * 4096 + dblk * 256;
  const ushort* ubase = u_bf + rowbase * 4096 + dblk * 256;
#pragma unroll
  for (int rr = 0; rr < 8; ++rr) {
    const int i = rr * 256 + tid;
    const int t = i >> 5, dof = (i & 31) << 3;
    gload16(dbase + (size_t)t * 4096 + dof, sD + i * 8);
    gload16(ubase + (size_t)t * 4096 + dof, sU + i * 8);
  }
  {
    const int rr2 = tid >> 2, seg = tid & 3;
    sB[tid] = *(const float4*)(xdbl + (rowbase + rr2) * 256 + 128 + seg * 4);
  }
  __syncthreads();

  float Ae[16];
#pragma unroll
  for (int n = 0; n < 16; ++n) Ae[n] = -__expf(A_log[(size_t)d * CN + n]);
  float h[16] = {};
  float S = 0.f;
  for (int t = 0; t < LC; ++t) {
    const float dl = b2f(sD[t * 256 + tid]);
    const float uu = b2f(sU[t * 256 + tid]);
    const float du = dl * uu;
    S += dl;
#pragma unroll
    for (int q = 0; q < 4; ++q) {
      float4 bq = sB[t * 4 + q];
      h[q * 4 + 0] = __expf(Ae[q * 4 + 0] * dl) * h[q * 4 + 0] + du * bq.x;
      h[q * 4 + 1] = __expf(Ae[q * 4 + 1] * dl) * h[q * 4 + 1] + du * bq.y;
      h[q * 4 + 2] = __expf(Ae[q * 4 + 2] * dl) * h[q * 4 + 2] + du * bq.z;
      h[q * 4 + 3] = __expf(Ae[q * 4 + 3] * dl) * h[q * 4 + 3] + du * bq.w;
    }
  }
  float4* Hp = (float4*)(Hc + ((((size_t)c * CB + b) * CDI + d) << 4));
#pragma unroll
  for (int q = 0; q < 4; ++q)
    Hp[q] = make_float4(h[q * 4 + 0], h[q * 4 + 1], h[q * 4 + 2], h[q * 4 + 3]);
  Ssum[((size_t)c * CB + b) * CDI + d] = S;
}

__global__ __launch_bounds__(256)
void scan_pass2_kernel(float* __restrict__ Hc, const float* __restrict__ Ssum,
                       const float* __restrict__ A_log) {
  const int t = blockIdx.x * 256 + threadIdx.x;
  const int n = t & 15, d = (t >> 4) & (CDI - 1), b = t >> 16;
  const float Ae = -__expf(A_log[(size_t)d * CN + n]);
  float h = 0.f;
  for (int c = 1; c < NC; ++c) {
    const size_t idxp = ((size_t)(c - 1) * CB + b) * CDI + d;
    const float P = __expf(Ae * Ssum[idxp]);
    h = P * h + Hc[idxp * 16 + n];
    Hc[idxp * 16 + n] = h;
  }
}

__global__ __launch_bounds__(256)
void scan_pass3_kernel(const ushort* __restrict__ delta_bf, const ushort* __restrict__ u_bf,
                       const float* __restrict__ xdbl, const ushort* __restrict__ xr,
                       const float* __restrict__ A_log, const float* __restrict__ Dvec,
                       const float* __restrict__ Hc, ushort* __restrict__ ybf) {
  __shared__ ushort sD[LC * 256];
  __shared__ ushort sU[LC * 256];
  __shared__ float4 sB[LC * 4];
  __shared__ float4 sC[LC * 4];
  const int blk = blockIdx.x;
  const int dblk = blk & 15, bc = blk >> 4;
  const int b = bc & (CB - 1), c = bc >> 1;
  const int tid = threadIdx.x;
  const int d = dblk * 256 + tid;
  const size_t rowbase = (size_t)b * CL + c * LC;

  const ushort* dbase = delta_bf + rowbase * 4096 + dblk * 256;
  const ushort* ubase = u_bf + rowbase * 4096 + dblk * 256;
#pragma unroll
  for (int rr = 0; rr < 8; ++rr) {
    const int i = rr * 256 + tid;
    const int t = i >> 5, dof = (i & 31) << 3;
    gload16(dbase + (size_t)t * 4096 + dof, sD + i * 8);
    gload16(ubase + (size_t)t * 4096 + dof, sU + i * 8);
  }
  {
    const int rr2 = tid >> 2, seg = tid & 3;
    sB[tid] = *(const float4*)(xdbl + (rowbase + rr2) * 256 + 128 + seg * 4);
    sC[tid] = *(const float4*)(xdbl + (rowbase + rr2) * 256 + 144 + seg * 4);
  }
  __syncthreads();

  float Ae[16];
#pragma unroll
  for (int n = 0; n < 16; ++n) Ae[n] = -__expf(A_log[(size_t)d * CN + n]);
  float h[16];
  if (c == 0) {
#pragma unroll
    for (int n = 0; n < 16; ++n) h[n] = 0.f;
  } else {
    const float4* Hp = (const float4*)(Hc + ((((size_t)(c - 1) * CB + b) * CDI + d) << 4));
#pragma unroll
    for (int q = 0; q < 4; ++q) {
      float4 hv = Hp[q];
      h[q * 4 + 0] = hv.x; h[q * 4 + 1] = hv.y; h[q * 4 + 2] = hv.z; h[q * 4 + 3] = hv.w;
    }
  }
  const float Dd = Dvec[d];
  for (int t = 0; t < LC; ++t) {
    const float res = b2f(xr[(rowbase + t) * 8192 + 4096 + d]);   // issue early
    const float dl = b2f(sD[t * 256 + tid]);
    const float uu = b2f(sU[t * 256 + tid]);
    const float du = dl * uu;
    float y = 0.f;
#pragma unroll
    for (int q = 0; q < 4; ++q) {
      float4 bq = sB[t * 4 + q];
      float4 cq = sC[t * 4 + q];
      h[q * 4 + 0] = __expf(Ae[q * 4 + 0] * dl) * h[q * 4 + 0] + du * bq.x;
      h[q * 4 + 1] = __expf(Ae[q * 4 + 1] * dl) * h[q * 4 + 1] + du * bq.y;
      h[q * 4 + 2] = __expf(Ae[q * 4 + 2] * dl) * h[q * 4 + 2] + du * bq.z;
      h[q * 4 + 3] = __expf(Ae[q * 4 + 3] * dl) * h[q * 4 + 3] + du * bq.w;
      y = fmaf(h[q * 4 + 0], cq.x, y);
      y = fmaf(h[q * 4 + 1], cq.y, y);
      y = fmaf(h[q * 4 + 2], cq.z, y);
      y = fmaf(h[q * 4 + 3], cq.w, y);
    }
    const float sres = res / (1.f + __expf(-res));
    ybf[(rowbase + t) * 4096 + d] = f2b((y + uu * Dd) * sres);
  }
}

// ---------------- host ----------------
extern "C" void kernel_launch(void* const* d_in, const int* in_sizes, int n_in,
                              void* d_out, int out_size, void* d_ws, size_t ws_size,
                              hipStream_t stream) {
  (void)in_sizes; (void)n_in; (void)out_size; (void)ws_size;
  const float* x       = (const float*)d_in[0];
  const float* in_w    = (const float*)d_in[1];
  const float* conv_w  = (const float*)d_in[2];
  const float* conv_b  = (const float*)d_in[3];
  const float* xproj_w = (const float*)d_in[4];
  const float* dt_w    = (const float*)d_in[5];
  const float* dt_b    = (const float*)d_in[6];
  const float* A_log   = (const float*)d_in[7];
  const float* Dvec    = (const float*)d_in[8];
  const float* out_w   = (const float*)d_in[9];
  float* out = (float*)d_out;
  char* ws = (char*)d_ws;
  const size_t MB = 1u << 20;

  ushort* xb    = (ushort*)(ws);             // 16 MiB
  float*  Hc    = (float*)(ws);              // 16 MiB  [NC,B,DI,16]
  ushort* wout  = (ushort*)(ws);             // 16 MiB
  ushort* wb1   = (ushort*)(ws + 16 * MB);   // 32 MiB  -> u_bf after GEMM1
  ushort* u_bf  = (ushort*)(ws + 16 * MB);   // 32 MiB
  ushort* xr    = (ushort*)(ws + 48 * MB);   // 64 MiB  [4096,8192] bf16
  float*  part  = (float*)(ws + 112 * MB);   // 16 MiB  [4,4096,256] fp32
  ushort* delta = (ushort*)(ws + 112 * MB);  // 32 MiB
  ushort* ybf   = (ushort*)(ws + 144 * MB);  // 32 MiB
  float*  xdbl  = (float*)(ws + 176 * MB);   // 4 MiB
  ushort* dlt   = (ushort*)(ws + 180 * MB);  // 1 MiB
  ushort* wxp   = (ushort*)(ws + 181 * MB);  // 2 MiB
  ushort* wdt   = (ushort*)(ws + 183 * MB);  // 1 MiB
  float*  Ssum  = (float*)(ws + 184 * MB);   // 1 MiB

  // fused early casts: x->xb, in_w->wb1, dt_w->wdt, xproj->wxp (padded)
  cast_all_kernel<<<(N4_X + N4_W1 + N4_DT + N4_XP) / 256, 256, 0, stream>>>(
      x, in_w, dt_w, xproj_w, xb, wb1, wdt, wxp);
  // GEMM1: x_and_res = x @ in_proj_w^T  [4096, 8192] bf16 (256^2 4-phase, 16x16)
  gemm256p_kernel<0><<<dim3(BLR / 256, (2 * CDI) / 256), 512, 0, stream>>>(
      xb, wb1, xr, 2 * CDI, CH);
  // conv + silu -> u
  conv_silu_kernel<<<(BLR * CDI / 8) / 256, 256, 0, stream>>>(xr, conv_w, conv_b, u_bf);
  // GEMM2 (split-K=4): x_dbl = u @ x_proj_w^T, N padded 160->256
  gemm_btk_kernel<<<dim3(BLR / 128, 2, KSL), 256, 0, stream>>>(
      u_bf, wxp, part, 256, CDI, CDI / KSL);
  reduce_xdbl_kernel<<<(BLR * 256 / 4) / 256, 256, 0, stream>>>(part, xdbl, dlt);
  // GEMM3: delta = softplus(dlt @ dt_proj_w^T + dt_b) (single-K-tile 256^2)
  gemm3_kernel<<<dim3(BLR / 256, CDI / 256), 512, 0, stream>>>(dlt, wdt, delta, dt_b);
  // chunk-parallel scan (LDS-staged tiles)
  scan_pass1_kernel<<<NC * CB * (CDI / 256), 256, 0, stream>>>(
      delta, u_bf, xdbl, A_log, Hc, Ssum);
  scan_pass2_kernel<<<(CB * CDI * CN) / 256, 256, 0, stream>>>(Hc, Ssum, A_log);
  scan_pass3_kernel<<<NC * CB * (CDI / 256), 256, 0, stream>>>(
      delta, u_bf, xdbl, xr, A_log, Dvec, Hc, ybf);
  // GEMM4: out = y @ out_proj_w^T  [4096,2048] fp32 (128x256 2-phase, 3-ring)
  cast_kernel<<<(CH * CDI / 4) / 256, 256, 0, stream>>>(out_w, wout, CH * CDI / 4);
  gemm128x256_kernel<1><<<dim3(BLR / 128, CH / 256), 512, 0, stream>>>(
      ybf, wout, out, CH, CDI);
}

// Round 18
// 542.371 us; speedup vs baseline: 1.0054x; 1.0054x over previous
//
#include <hip/hip_runtime.h>
#include <hip/hip_bf16.h>
#include <stdint.h>

#define DEV static __device__ __forceinline__

typedef __attribute__((ext_vector_type(8))) short short8;
typedef __attribute__((ext_vector_type(4))) float f32x4;
typedef __attribute__((address_space(3))) void lds_void;
typedef __attribute__((address_space(1))) void glb_void;

constexpr int CB = 2, CL = 2048, CH = 2048, CDI = 4096, CN = 16, CDTR = 128;
constexpr int BLR = CB * CL;   // 4096 total rows (b,l)
constexpr int NC = 32, LC = 64;  // scan chunks x chunk length
constexpr int KSL = 4;           // GEMM2 split-K slices

DEV ushort f2b(float f) {
  union { float f; uint32_t u; } v; v.f = f;
  uint32_t u = v.u;
  return (ushort)((u + 0x7fffu + ((u >> 16) & 1u)) >> 16);
}
DEV float b2f(ushort b) {
  union { uint32_t u; float f; } v; v.u = ((uint32_t)b) << 16;
  return v.f;
}
DEV void gload16(const ushort* g, ushort* l) {
  __builtin_amdgcn_global_load_lds((const glb_void*)g, (lds_void*)l, 16, 0, 0);
}
DEV f32x4 mfma16(short8 a, short8 b, f32x4 c) {
  return __builtin_amdgcn_mfma_f32_16x16x32_bf16(a, b, c, 0, 0, 0);
}

// ---------------- fused casts (x, in_w, dt_w, xproj-pad [, out_w]) ----------------
constexpr int N4_X  = BLR * CH / 4;
constexpr int N4_W1 = 2 * CDI * CH / 4;
constexpr int N4_DT = CDI * CDTR / 4;
constexpr int N4_XP = 256 * 4096 / 4;
constexpr int N4_OW = CH * CDI / 4;
__global__ void cast_all_kernel(const float* __restrict__ x, const float* __restrict__ in_w,
                                const float* __restrict__ dt_w, const float* __restrict__ xp_w,
                                const float* __restrict__ ow_w,
                                ushort* __restrict__ xb, ushort* __restrict__ wb1,
                                ushort* __restrict__ wdt, ushort* __restrict__ wxp,
                                ushort* __restrict__ wout) {
  int i = blockIdx.x * 256 + threadIdx.x;
  const float* src; ushort* dst; int idx;
  if (i < N4_X) { src = x; dst = xb; idx = i; }
  else if (i < N4_X + N4_W1) { src = in_w; dst = wb1; idx = i - N4_X; }
  else if (i < N4_X + N4_W1 + N4_DT) { src = dt_w; dst = wdt; idx = i - N4_X - N4_W1; }
  else if (i < N4_X + N4_W1 + N4_DT + N4_XP) {
    idx = i - (N4_X + N4_W1 + N4_DT);
    int e = idx * 4;
    int rr = e >> 12;
    ushort4 o;
    if (rr < 160) {
      float4 v = *(const float4*)(xp_w + e);
      o = make_ushort4(f2b(v.x), f2b(v.y), f2b(v.z), f2b(v.w));
    } else o = make_ushort4(0, 0, 0, 0);
    *(ushort4*)(wxp + e) = o;
    return;
  } else {
    idx = i - (N4_X + N4_W1 + N4_DT + N4_XP);
    if (idx >= N4_OW || wout == nullptr) return;
    src = ow_w; dst = wout;
  }
  float4 v = *(const float4*)(src + (size_t)idx * 4);
  *(ushort4*)(dst + (size_t)idx * 4) = make_ushort4(f2b(v.x), f2b(v.y), f2b(v.z), f2b(v.w));
}

__global__ void cast_kernel(const float* __restrict__ in, ushort* __restrict__ out, int n4) {
  int i = blockIdx.x * blockDim.x + threadIdx.x;
  if (i >= n4) return;
  float4 v = *(const float4*)(in + (size_t)i * 4);
  *(ushort4*)(out + (size_t)i * 4) = make_ushort4(f2b(v.x), f2b(v.y), f2b(v.z), f2b(v.w));
}

// ---------------- depthwise causal conv1d + silu (8 d / thread) ----------------
__global__ void conv_silu_kernel(const ushort* __restrict__ xr, const float* __restrict__ w,
                                 const float* __restrict__ bias, ushort* __restrict__ u) {
  int t = blockIdx.x * blockDim.x + threadIdx.x;
  if (t >= BLR * CDI / 8) return;
  const int d8 = (t & (CDI / 8 - 1)) << 3;
  const int bl = t >> 9;
  const int l = bl & (CL - 1);
  float a[8];
  {
    float4 b0 = *(const float4*)(bias + d8);
    float4 b1 = *(const float4*)(bias + d8 + 4);
    a[0] = b0.x; a[1] = b0.y; a[2] = b0.z; a[3] = b0.w;
    a[4] = b1.x; a[5] = b1.y; a[6] = b1.z; a[7] = b1.w;
  }
  float wk[8][4];
#pragma unroll
  for (int j = 0; j < 8; ++j) {
    float4 wj = *(const float4*)(w + (size_t)(d8 + j) * 4);
    wk[j][0] = wj.x; wk[j][1] = wj.y; wk[j][2] = wj.z; wk[j][3] = wj.w;
  }
#pragma unroll
  for (int k = 0; k < 4; ++k) {
    if (l - 3 + k >= 0) {
      short8 xv = *(const short8*)(xr + (size_t)(bl - 3 + k) * 8192 + d8);
#pragma unroll
      for (int j = 0; j < 8; ++j)
        a[j] = fmaf(wk[j][k], b2f((ushort)xv[j]), a[j]);
    }
  }
  short8 o;
#pragma unroll
  for (int j = 0; j < 8; ++j) {
    float s = a[j] / (1.f + __expf(-a[j]));
    o[j] = (short)f2b(s);
  }
  *(short8*)(u + (size_t)bl * 4096 + d8) = o;
}

// ---------------- 256x256 4-phase pipelined GEMM (GEMM1; proven R7) ----------------
template<int EPI>
__global__ __launch_bounds__(512, 1)
void gemm256p_kernel(const ushort* __restrict__ A, const ushort* __restrict__ Bw,
                     void* __restrict__ Cp, int N, int K) {
  __shared__ ushort sA[2][16384];
  __shared__ ushort sB[2][16384];
  const int tid = threadIdx.x;
  const int bm = blockIdx.x, bn = blockIdx.y;
  const int wid = tid >> 6, l = tid & 63;
  const int wr = wid >> 2, wc = wid & 3;
  const int q = l >> 4, r = l & 15;
  const int rx = r & 7;
  const int nt = K >> 6;

  const ushort* Ab = A + (size_t)bm * 256 * K;
  const ushort* Bb = Bw + (size_t)bn * 256 * K;

  const int srow = tid >> 3;
  const int sxor = (tid & 7) ^ (srow & 7);

  auto stageA = [&](int T, int j) {
    const int Ts = (T < nt) ? T : (nt - 1);
    gload16(Ab + (size_t)(j * 64 + srow) * K + Ts * 64 + sxor * 8,
            &sA[T & 1][0] + j * 4096 + tid * 8);
  };
  auto stageB = [&](int T, int j) {
    const int Ts = (T < nt) ? T : (nt - 1);
    gload16(Bb + (size_t)(j * 64 + srow) * K + Ts * 64 + sxor * 8,
            &sB[T & 1][0] + j * 4096 + tid * 8);
  };

  const int sl0 = (q ^ rx) * 8;
  const int sl1 = ((4 + q) ^ rx) * 8;

  f32x4 acc[8][4] = {};

  stageA(0, 1); stageA(0, 3);
  stageB(0, 0); stageA(0, 0);
  stageB(0, 2); stageA(0, 2);
  stageB(0, 1); stageB(0, 3);
  stageA(1, 1); stageA(1, 3);
  asm volatile("s_waitcnt vmcnt(2)" ::: "memory");
  __builtin_amdgcn_s_barrier();

#define PHASE(M0, M1, S0, S1, LAST)                                        \
  {                                                                        \
    const int ra0 = (wr * 128 + (M0) * 16 + r) * 64;                       \
    const int ra1 = (wr * 128 + (M1) * 16 + r) * 64;                       \
    short8 a00 = *(const short8*)(At + ra0 + sl0);                         \
    short8 a01 = *(const short8*)(At + ra0 + sl1);                         \
    short8 a10 = *(const short8*)(At + ra1 + sl0);                         \
    short8 a11 = *(const short8*)(At + ra1 + sl1);                         \
    S0; S1;                                                                \
    if (LAST) asm volatile("s_waitcnt vmcnt(2)" ::: "memory");             \
    __builtin_amdgcn_s_barrier();                                          \
    asm volatile("s_waitcnt lgkmcnt(0)" ::: "memory");                     \
    __builtin_amdgcn_sched_barrier(0);                                     \
    __builtin_amdgcn_s_setprio(1);                                         \
    _Pragma("unroll")                                                      \
    for (int n = 0; n < 4; ++n) {                                          \
      acc[M0][n] = mfma16(a00, bf[n][0], acc[M0][n]);                      \
      acc[M0][n] = mfma16(a01, bf[n][1], acc[M0][n]);                      \
      acc[M1][n] = mfma16(a10, bf[n][0], acc[M1][n]);                      \
      acc[M1][n] = mfma16(a11, bf[n][1], acc[M1][n]);                      \
    }                                                                      \
    __builtin_amdgcn_s_setprio(0);                                         \
    __builtin_amdgcn_sched_barrier(0);                                     \
    __builtin_amdgcn_s_barrier();                                          \
  }

  for (int t = 0; t < nt; ++t) {
    const ushort* At = &sA[t & 1][0];
    const ushort* Bt = &sB[t & 1][0];
    short8 bf[4][2];
#pragma unroll
    for (int n = 0; n < 4; ++n) {
      const int br = (wc * 64 + n * 16 + r) * 64;
      bf[n][0] = *(const short8*)(Bt + br + sl0);
      bf[n][1] = *(const short8*)(Bt + br + sl1);
    }
    PHASE(6, 7, stageB(t + 1, 0), stageA(t + 1, 0), false)
    PHASE(4, 5, stageB(t + 1, 2), stageA(t + 1, 2), false)
    PHASE(2, 3, stageB(t + 1, 1), stageB(t + 1, 3), false)
    PHASE(0, 1, stageA(t + 2, 1), stageA(t + 2, 3), true)
  }
#undef PHASE

  const int m0g = bm * 256 + wr * 128;
  const int n0g = bn * 256 + wc * 64;
#pragma unroll
  for (int m = 0; m < 8; ++m)
#pragma unroll
    for (int n = 0; n < 4; ++n)
#pragma unroll
      for (int v = 0; v < 4; ++v) {
        const int grow = m0g + m * 16 + q * 4 + v;
        const int gcol = n0g + n * 16 + r;
        if (EPI == 0) ((ushort*)Cp)[(size_t)grow * N + gcol] = f2b(acc[m][n][v]);
        else          ((float*)Cp)[(size_t)grow * N + gcol]  = acc[m][n][v];
      }
}

// ---------------- GEMM4: 128x256 2-phase, 3-buffer LDS ring (proven R11) --------
template<int EPI>
__global__ __launch_bounds__(512, 1)
void gemm128x256_kernel(const ushort* __restrict__ A, const ushort* __restrict__ Bw,
                        void* __restrict__ Cp, int N, int K) {
  __shared__ ushort sA[3][8192];
  __shared__ ushort sB[3][16384];
  const int tid = threadIdx.x;
  const int bm = blockIdx.x, bn = blockIdx.y;
  const int wid = tid >> 6, l = tid & 63;
  const int wr = wid >> 2, wc = wid & 3;
  const int q = l >> 4, r = l & 15;
  const int rx = r & 7;
  const int nt = K >> 6;

  const ushort* Ab = A + (size_t)bm * 128 * K;
  const ushort* Bb = Bw + (size_t)bn * 256 * K;

  const int srow = tid >> 3;
  const int sxor = (tid & 7) ^ (srow & 7);

  auto stageA = [&](int T, int buf, int j) {
    const int Ts = (T < nt) ? T : (nt - 1);
    gload16(Ab + (size_t)(j * 64 + srow) * K + Ts * 64 + sxor * 8,
            &sA[buf][0] + j * 4096 + tid * 8);
  };
  auto stageB = [&](int T, int buf, int j) {
    const int Ts = (T < nt) ? T : (nt - 1);
    gload16(Bb + (size_t)(j * 64 + srow) * K + Ts * 64 + sxor * 8,
            &sB[buf][0] + j * 4096 + tid * 8);
  };

  const int sl0 = (q ^ rx) * 8;
  const int sl1 = ((4 + q) ^ rx) * 8;

  f32x4 acc[4][4] = {};

  stageA(0, 0, 0); stageA(0, 0, 1);
  stageB(0, 0, 0); stageB(0, 0, 1); stageB(0, 0, 2); stageB(0, 0, 3);
  stageA(1, 1, 0); stageA(1, 1, 1);
  asm volatile("s_waitcnt vmcnt(2)" ::: "memory");
  __builtin_amdgcn_s_barrier();

  int c0 = 0;
  for (int t = 0; t < nt; ++t) {
    const int c1 = (c0 == 2) ? 0 : c0 + 1;
    const int c2 = (c1 == 2) ? 0 : c1 + 1;
    const ushort* At = &sA[c0][0];
    const ushort* Bt = &sB[c0][0];
    short8 bf[4][2];
#pragma unroll
    for (int n = 0; n < 4; ++n) {
      const int br = (wc * 64 + n * 16 + r) * 64;
      bf[n][0] = *(const short8*)(Bt + br + sl0);
      bf[n][1] = *(const short8*)(Bt + br + sl1);
    }
    {
      const int ra0 = (wr * 64 + 2 * 16 + r) * 64;
      const int ra1 = (wr * 64 + 3 * 16 + r) * 64;
      short8 a00 = *(const short8*)(At + ra0 + sl0);
      short8 a01 = *(const short8*)(At + ra0 + sl1);
      short8 a10 = *(const short8*)(At + ra1 + sl0);
      short8 a11 = *(const short8*)(At + ra1 + sl1);
      stageB(t + 1, c1, 0); stageB(t + 1, c1, 1); stageB(t + 1, c1, 2);
      __builtin_amdgcn_s_barrier();
      asm volatile("s_waitcnt lgkmcnt(0)" ::: "memory");
      __builtin_amdgcn_sched_barrier(0);
      __builtin_amdgcn_s_setprio(1);
#pragma unroll
      for (int n = 0; n < 4; ++n) {
        acc[2][n] = mfma16(a00, bf[n][0], acc[2][n]);
        acc[2][n] = mfma16(a01, bf[n][1], acc[2][n]);
        acc[3][n] = mfma16(a10, bf[n][0], acc[3][n]);
        acc[3][n] = mfma16(a11, bf[n][1], acc[3][n]);
      }
      __builtin_amdgcn_s_setprio(0);
      __builtin_amdgcn_sched_barrier(0);
      __builtin_amdgcn_s_barrier();
    }
    {
      const int ra0 = (wr * 64 + 0 * 16 + r) * 64;
      const int ra1 = (wr * 64 + 1 * 16 + r) * 64;
      short8 a00 = *(const short8*)(At + ra0 + sl0);
      short8 a01 = *(const short8*)(At + ra0 + sl1);
      short8 a10 = *(const short8*)(At + ra1 + sl0);
      short8 a11 = *(const short8*)(At + ra1 + sl1);
      stageB(t + 1, c1, 3); stageA(t + 2, c2, 0); stageA(t + 2, c2, 1);
      asm volatile("s_waitcnt vmcnt(2)" ::: "memory");
      __builtin_amdgcn_s_barrier();
      asm volatile("s_waitcnt lgkmcnt(0)" ::: "memory");
      __builtin_amdgcn_sched_barrier(0);
      __builtin_amdgcn_s_setprio(1);
#pragma unroll
      for (int n = 0; n < 4; ++n) {
        acc[0][n] = mfma16(a00, bf[n][0], acc[0][n]);
        acc[0][n] = mfma16(a01, bf[n][1], acc[0][n]);
        acc[1][n] = mfma16(a10, bf[n][0], acc[1][n]);
        acc[1][n] = mfma16(a11, bf[n][1], acc[1][n]);
      }
      __builtin_amdgcn_s_setprio(0);
      __builtin_amdgcn_sched_barrier(0);
      __builtin_amdgcn_s_barrier();
    }
    c0 = c1;
  }

  const int m0g = bm * 128 + wr * 64;
  const int n0g = bn * 256 + wc * 64;
#pragma unroll
  for (int m = 0; m < 4; ++m)
#pragma unroll
    for (int n = 0; n < 4; ++n)
#pragma unroll
      for (int v = 0; v < 4; ++v) {
        const int grow = m0g + m * 16 + q * 4 + v;
        const int gcol = n0g + n * 16 + r;
        if (EPI == 0) ((ushort*)Cp)[(size_t)grow * N + gcol] = f2b(acc[m][n][v]);
        else          ((float*)Cp)[(size_t)grow * N + gcol]  = acc[m][n][v];
      }
}

// ---------------- GEMM3: single-K-tile 256x256, BK=128 (whole K in LDS) ----------
__global__ __launch_bounds__(512, 1)
void gemm3_kernel(const ushort* __restrict__ A, const ushort* __restrict__ Bw,
                  ushort* __restrict__ Cp, const float* __restrict__ bias) {
  __shared__ ushort sA[256 * 128];
  __shared__ ushort sB[256 * 128];
  const int tid = threadIdx.x;
  const int bm = blockIdx.x, bn = blockIdx.y;
  const int wid = tid >> 6, l = tid & 63;
  const int wr = wid >> 2, wc = wid & 3;
  const int q = l >> 4, r = l & 15;

  const ushort* Ab = A + (size_t)bm * 256 * 128;
  const ushort* Bb = Bw + (size_t)bn * 256 * 128;
#pragma unroll
  for (int i = 0; i < 8; ++i) {
    const int c = i * 512 + tid;
    const int row = c >> 4, p = c & 15;
    const int lsl = p ^ (row & 7);
    gload16(Ab + (size_t)row * 128 + lsl * 8, sA + c * 8);
    gload16(Bb + (size_t)row * 128 + lsl * 8, sB + c * 8);
  }
  __syncthreads();

  f32x4 acc[8][4] = {};
  short8 bf[4][4];
#pragma unroll
  for (int n = 0; n < 4; ++n) {
    const int brow = wc * 64 + n * 16 + r;
#pragma unroll
    for (int ks = 0; ks < 4; ++ks) {
      const int p = (ks * 4 + q) ^ (brow & 7);
      bf[n][ks] = *(const short8*)(sB + brow * 128 + p * 8);
    }
  }
#pragma unroll
  for (int m = 0; m < 8; ++m) {
    const int arow = wr * 128 + m * 16 + r;
    short8 af[4];
#pragma unroll
    for (int ks = 0; ks < 4; ++ks) {
      const int p = (ks * 4 + q) ^ (arow & 7);
      af[ks] = *(const short8*)(sA + arow * 128 + p * 8);
    }
#pragma unroll
    for (int ks = 0; ks < 4; ++ks)
#pragma unroll
      for (int n = 0; n < 4; ++n)
        acc[m][n] = mfma16(af[ks], bf[n][ks], acc[m][n]);
  }

  const int m0g = bm * 256 + wr * 128;
  const int n0g = bn * 256 + wc * 64;
#pragma unroll
  for (int m = 0; m < 8; ++m)
#pragma unroll
    for (int n = 0; n < 4; ++n)
#pragma unroll
      for (int v = 0; v < 4; ++v) {
        const int grow = m0g + m * 16 + q * 4 + v;
        const int gcol = n0g + n * 16 + r;
        float xv = acc[m][n][v] + bias[gcol];
        float sp = xv > 20.f ? xv : log1pf(__expf(xv));
        Cp[(size_t)grow * 4096 + gcol] = f2b(sp);
      }
}

// ---------------- split-K GEMM (GEMM2) ----------------
__global__ __launch_bounds__(256, 4)
void gemm_btk_kernel(const ushort* __restrict__ A, const ushort* __restrict__ Bw,
                     float* __restrict__ Cpart, int N, int Ktot, int Ksl) {
  __shared__ ushort sA[128 * 32];
  __shared__ ushort sB[128 * 32];
  const int tid = threadIdx.x;
  const int bm = blockIdx.x, bn = blockIdx.y, z = blockIdx.z;
  const int w = tid >> 6, l = tid & 63;
  const int wr = w >> 1, wc = w & 1;
  const int q = l >> 4, r = l & 15;

  f32x4 acc[4][4] = {};

  const ushort* Ab = A + (size_t)bm * 128 * Ktot + z * Ksl;
  const ushort* Bb = Bw + (size_t)bn * 128 * Ktot + z * Ksl;
  const int nk = Ksl >> 5;
  for (int kt = 0; kt < nk; ++kt) {
    const int k0 = kt << 5;
#pragma unroll
    for (int i = 0; i < 2; ++i) {
      const int chunk = i * 256 + tid;
      const int row = chunk >> 2;
      const int cofs = (chunk & 3) << 3;
      gload16(Ab + (size_t)row * Ktot + k0 + cofs, sA + chunk * 8);
      gload16(Bb + (size_t)row * Ktot + k0 + cofs, sB + chunk * 8);
    }
    __syncthreads();
    short8 af[4], bfg[4];
#pragma unroll
    for (int i = 0; i < 4; ++i) {
      af[i]  = *(const short8*)(sA + (wr * 64 + i * 16 + r) * 32 + q * 8);
      bfg[i] = *(const short8*)(sB + (wc * 64 + i * 16 + r) * 32 + q * 8);
    }
#pragma unroll
    for (int i = 0; i < 4; ++i)
#pragma unroll
      for (int j = 0; j < 4; ++j)
        acc[i][j] = mfma16(af[i], bfg[j], acc[i][j]);
    __syncthreads();
  }

  float* Cz = Cpart + (size_t)z * BLR * N;
  const int m0 = bm * 128 + wr * 64;
  const int n0 = bn * 128 + wc * 64;
#pragma unroll
  for (int i = 0; i < 4; ++i)
#pragma unroll
    for (int j = 0; j < 4; ++j)
#pragma unroll
      for (int v = 0; v < 4; ++v)
        Cz[(size_t)(m0 + i * 16 + q * 4 + v) * N + (n0 + j * 16 + r)] = acc[i][j][v];
}

__global__ __launch_bounds__(256)
void reduce_xdbl_kernel(const float* __restrict__ part, float* __restrict__ xdbl,
                        ushort* __restrict__ dlt) {
  const int i = blockIdx.x * 256 + threadIdx.x;
  const int idx = i * 4;
  const int row = idx >> 8, col = idx & 255;
  float4 s = make_float4(0.f, 0.f, 0.f, 0.f);
#pragma unroll
  for (int z = 0; z < KSL; ++z) {
    float4 v = *(const float4*)(part + (size_t)z * BLR * 256 + idx);
    s.x += v.x; s.y += v.y; s.z += v.z; s.w += v.w;
  }
  *(float4*)(xdbl + idx) = s;
  if (col < 128) {
    *(ushort4*)(dlt + (size_t)row * 128 + col) =
        make_ushort4(f2b(s.x), f2b(s.y), f2b(s.z), f2b(s.w));
  }
}

// ---------------- chunk-parallel selective scan (LDS-staged tiles) ----------------
__global__ __launch_bounds__(256)
void scan_pass1_kernel(const ushort* __restrict__ delta_bf, const ushort* __restrict__ u_bf,
                       const float* __restrict__ xdbl, const float* __restrict__ A_log,
                       float* __restrict__ Hc, float* __restrict__ Ssum) {
  __shared__ ushort sD[LC * 256];
  __shared__ ushort sU[LC * 256];
  __shared__ float4 sB[LC * 4];
  const int blk = blockIdx.x;
  const int dblk = blk & 15, bc = blk >> 4;
  const int b = bc & (CB - 1), c = bc >> 1;
  const int tid = threadIdx.x;
  const int d = dblk * 256 + tid;
  const size_t rowbase = (size_t)b * CL + c * LC;

  const ushort* dbase = delta_bf + rowbase * 4096 + dblk * 256;
  const ushort* ubase = u_bf + rowbase * 4096 + dblk * 256;
#pragma unroll
  for (int rr = 0; rr < 8; ++rr) {
    const int i = rr * 256 + tid;
    const int t = i >> 5, dof = (i & 31) << 3;
    gload16(dbase + (size_t)t * 4096 + dof, sD + i * 8);
    gload16(ubase + (size_t)t * 4096 + dof, sU + i * 8);
  }
  {
    const int rr2 = tid >> 2, seg = tid & 3;
    sB[tid] = *(const float4*)(xdbl + (rowbase + rr2) * 256 + 128 + seg * 4);
  }
  __syncthreads();

  float Ae[16];
#pragma unroll
  for (int n = 0; n < 16; ++n) Ae[n] = -__expf(A_log[(size_t)d * CN + n]);
  float h[16] = {};
  float S = 0.f;
  for (int t = 0; t < LC; ++t) {
    const float dl = b2f(sD[t * 256 + tid]);
    const float uu = b2f(sU[t * 256 + tid]);
    const float du = dl * uu;
    S += dl;
#pragma unroll
    for (int q = 0; q < 4; ++q) {
      float4 bq = sB[t * 4 + q];
      h[q * 4 + 0] = __expf(Ae[q * 4 + 0] * dl) * h[q * 4 + 0] + du * bq.x;
      h[q * 4 + 1] = __expf(Ae[q * 4 + 1] * dl) * h[q * 4 + 1] + du * bq.y;
      h[q * 4 + 2] = __expf(Ae[q * 4 + 2] * dl) * h[q * 4 + 2] + du * bq.z;
      h[q * 4 + 3] = __expf(Ae[q * 4 + 3] * dl) * h[q * 4 + 3] + du * bq.w;
    }
  }
  float4* Hp = (float4*)(Hc + ((((size_t)c * CB + b) * CDI + d) << 4));
#pragma unroll
  for (int q = 0; q < 4; ++q)
    Hp[q] = make_float4(h[q * 4 + 0], h[q * 4 + 1], h[q * 4 + 2], h[q * 4 + 3]);
  Ssum[((size_t)c * CB + b) * CDI + d] = S;
}

__global__ __launch_bounds__(256)
void scan_pass2_kernel(float* __restrict__ Hc, const float* __restrict__ Ssum,
                       const float* __restrict__ A_log) {
  const int t = blockIdx.x * 256 + threadIdx.x;
  const int n = t & 15, d = (t >> 4) & (CDI - 1), b = t >> 16;
  const float Ae = -__expf(A_log[(size_t)d * CN + n]);
  float h = 0.f;
#pragma unroll
  for (int c = 1; c < NC; ++c) {
    const size_t idxp = ((size_t)(c - 1) * CB + b) * CDI + d;
    const float P = __expf(Ae * Ssum[idxp]);
    h = P * h + Hc[idxp * 16 + n];
    Hc[idxp * 16 + n] = h;
  }
}

__global__ __launch_bounds__(256)
void scan_pass3_kernel(const ushort* __restrict__ delta_bf, const ushort* __restrict__ u_bf,
                       const float* __restrict__ xdbl, const ushort* __restrict__ xr,
                       const float* __restrict__ A_log, const float* __restrict__ Dvec,
                       const float* __restrict__ Hc, ushort* __restrict__ ybf) {
  __shared__ ushort sD[LC * 256];
  __shared__ ushort sU[LC * 256];
  __shared__ float4 sB[LC * 4];
  __shared__ float4 sC[LC * 4];
  const int blk = blockIdx.x;
  const int dblk = blk & 15, bc = blk >> 4;
  const int b = bc & (CB - 1), c = bc >> 1;
  const int tid = threadIdx.x;
  const int d = dblk * 256 + tid;
  const size_t rowbase = (size_t)b * CL + c * LC;

  const ushort* dbase = delta_bf + rowbase * 4096 + dblk * 256;
  const ushort* ubase = u_bf + rowbase * 4096 + dblk * 256;
#pragma unroll
  for (int rr = 0; rr < 8; ++rr) {
    const int i = rr * 256 + tid;
    const int t = i >> 5, dof = (i & 31) << 3;
    gload16(dbase + (size_t)t * 4096 + dof, sD + i * 8);
    gload16(ubase + (size_t)t * 4096 + dof, sU + i * 8);
  }
  {
    const int rr2 = tid >> 2, seg = tid & 3;
    sB[tid] = *(const float4*)(xdbl + (rowbase + rr2) * 256 + 128 + seg * 4);
    sC[tid] = *(const float4*)(xdbl + (rowbase + rr2) * 256 + 144 + seg * 4);
  }
  __syncthreads();

  float Ae[16];
#pragma unroll
  for (int n = 0; n < 16; ++n) Ae[n] = -__expf(A_log[(size_t)d * CN + n]);
  float h[16];
  if (c == 0) {
#pragma unroll
    for (int n = 0; n < 16; ++n) h[n] = 0.f;
  } else {
    const float4* Hp = (const float4*)(Hc + ((((size_t)(c - 1) * CB + b) * CDI + d) << 4));
#pragma unroll
    for (int q = 0; q < 4; ++q) {
      float4 hv = Hp[q];
      h[q * 4 + 0] = hv.x; h[q * 4 + 1] = hv.y; h[q * 4 + 2] = hv.z; h[q * 4 + 3] = hv.w;
    }
  }
  const float Dd = Dvec[d];
  for (int t = 0; t < LC; ++t) {
    const float res = b2f(xr[(rowbase + t) * 8192 + 4096 + d]);
    const float dl = b2f(sD[t * 256 + tid]);
    const float uu = b2f(sU[t * 256 + tid]);
    const float du = dl * uu;
    float y = 0.f;
#pragma unroll
    for (int q = 0; q < 4; ++q) {
      float4 bq = sB[t * 4 + q];
      float4 cq = sC[t * 4 + q];
      h[q * 4 + 0] = __expf(Ae[q * 4 + 0] * dl) * h[q * 4 + 0] + du * bq.x;
      h[q * 4 + 1] = __expf(Ae[q * 4 + 1] * dl) * h[q * 4 + 1] + du * bq.y;
      h[q * 4 + 2] = __expf(Ae[q * 4 + 2] * dl) * h[q * 4 + 2] + du * bq.z;
      h[q * 4 + 3] = __expf(Ae[q * 4 + 3] * dl) * h[q * 4 + 3] + du * bq.w;
      y = fmaf(h[q * 4 + 0], cq.x, y);
      y = fmaf(h[q * 4 + 1], cq.y, y);
      y = fmaf(h[q * 4 + 2], cq.z, y);
      y = fmaf(h[q * 4 + 3], cq.w, y);
    }
    const float sres = res / (1.f + __expf(-res));
    ybf[(rowbase + t) * 4096 + d] = f2b((y + uu * Dd) * sres);
  }
}

// ---------------- host ----------------
extern "C" void kernel_launch(void* const* d_in, const int* in_sizes, int n_in,
                              void* d_out, int out_size, void* d_ws, size_t ws_size,
                              hipStream_t stream) {
  (void)in_sizes; (void)n_in; (void)out_size;
  const float* x       = (const float*)d_in[0];
  const float* in_w    = (const float*)d_in[1];
  const float* conv_w  = (const float*)d_in[2];
  const float* conv_b  = (const float*)d_in[3];
  const float* xproj_w = (const float*)d_in[4];
  const float* dt_w    = (const float*)d_in[5];
  const float* dt_b    = (const float*)d_in[6];
  const float* A_log   = (const float*)d_in[7];
  const float* Dvec    = (const float*)d_in[8];
  const float* out_w   = (const float*)d_in[9];
  float* out = (float*)d_out;
  char* ws = (char*)d_ws;
  const size_t MB = 1u << 20;

  ushort* xb    = (ushort*)(ws);             // 16 MiB
  float*  Hc    = (float*)(ws);              // 16 MiB  [NC,B,DI,16]
  ushort* wb1   = (ushort*)(ws + 16 * MB);   // 32 MiB  -> u_bf after GEMM1
  ushort* u_bf  = (ushort*)(ws + 16 * MB);   // 32 MiB
  ushort* xr    = (ushort*)(ws + 48 * MB);   // 64 MiB  [4096,8192] bf16
  float*  part  = (float*)(ws + 112 * MB);   // 16 MiB  [4,4096,256] fp32
  ushort* delta = (ushort*)(ws + 112 * MB);  // 32 MiB
  ushort* ybf   = (ushort*)(ws + 144 * MB);  // 32 MiB
  float*  xdbl  = (float*)(ws + 176 * MB);   // 4 MiB
  ushort* dlt   = (ushort*)(ws + 180 * MB);  // 1 MiB
  ushort* wxp   = (ushort*)(ws + 181 * MB);  // 2 MiB
  ushort* wdt   = (ushort*)(ws + 183 * MB);  // 1 MiB
  float*  Ssum  = (float*)(ws + 184 * MB);   // 1 MiB

  // out_w bf16 buffer: prefer non-aliased region at 185 MiB (early cast fused
  // into cast_all); fall back to late cast into ws+0 (after scan frees Hc).
  const bool early_wout = ws_size >= 201 * MB;
  ushort* wout = early_wout ? (ushort*)(ws + 185 * MB) : (ushort*)(ws);

  const int castN = N4_X + N4_W1 + N4_DT + N4_XP + (early_wout ? N4_OW : 0);
  cast_all_kernel<<<(castN + 255) / 256, 256, 0, stream>>>(
      x, in_w, dt_w, xproj_w, out_w, xb, wb1, wdt, wxp,
      early_wout ? wout : nullptr);
  // GEMM1: x_and_res = x @ in_proj_w^T  [4096, 8192] bf16 (256^2 4-phase, 16x16)
  gemm256p_kernel<0><<<dim3(BLR / 256, (2 * CDI) / 256), 512, 0, stream>>>(
      xb, wb1, xr, 2 * CDI, CH);
  // conv + silu -> u
  conv_silu_kernel<<<(BLR * CDI / 8) / 256, 256, 0, stream>>>(xr, conv_w, conv_b, u_bf);
  // GEMM2 (split-K=4): x_dbl = u @ x_proj_w^T, N padded 160->256
  gemm_btk_kernel<<<dim3(BLR / 128, 2, KSL), 256, 0, stream>>>(
      u_bf, wxp, part, 256, CDI, CDI / KSL);
  reduce_xdbl_kernel<<<(BLR * 256 / 4) / 256, 256, 0, stream>>>(part, xdbl, dlt);
  // GEMM3: delta = softplus(dlt @ dt_proj_w^T + dt_b) (single-K-tile 256^2)
  gemm3_kernel<<<dim3(BLR / 256, CDI / 256), 512, 0, stream>>>(dlt, wdt, delta, dt_b);
  // chunk-parallel scan (LDS-staged tiles)
  scan_pass1_kernel<<<NC * CB * (CDI / 256), 256, 0, stream>>>(
      delta, u_bf, xdbl, A_log, Hc, Ssum);
  scan_pass2_kernel<<<(CB * CDI * CN) / 256, 256, 0, stream>>>(Hc, Ssum, A_log);
  scan_pass3_kernel<<<NC * CB * (CDI / 256), 256, 0, stream>>>(
      delta, u_bf, xdbl, xr, A_log, Dvec, Hc, ybf);
  // GEMM4: out = y @ out_proj_w^T  [4096,2048] fp32 (128x256 2-phase, 3-ring)
  if (!early_wout)
    cast_kernel<<<(CH * CDI / 4) / 256, 256, 0, stream>>>(out_w, wout, CH * CDI / 4);
  gemm128x256_kernel<1><<<dim3(BLR / 128, CH / 256), 512, 0, stream>>>(
      ybf, wout, out, CH, CDI);
}